// Round 5
// baseline (160.113 us; speedup 1.0000x reference)
//
#include <hip/hip_runtime.h>
#include <hip/hip_fp16.h>

typedef _Float16 h8 __attribute__((ext_vector_type(8)));
typedef _Float16 h2v __attribute__((ext_vector_type(2)));
typedef __fp16 fp16x2 __attribute__((ext_vector_type(2)));
typedef float f32x4 __attribute__((ext_vector_type(4)));

#define HW 3136    // 56*56
#define XROW 16    // xsb row stride (u32): with 2*XSEG%32==8, phase-D x reads are a
                   //   perfect 2x bank cover per wave (free)
#define XSEG 148   // xsb segment stride (u32)
#define PS2 456    // wgt pixel stride (u16): 448 slots + 8 pad; 912B, 16B-aligned
#define WGT_W 3648 // wgt region words (16 px * 228); aliased as xt[16][264] during stage
#define XSB_W 2368 // xsb words (16 * 148)
#define YB_W  768  // yb words: 16 px * 96 u16
#define SMEM_W (WGT_W + XSB_W + YB_W)   // 6784 words = 27136 B = 53*512 -> 6 blocks/CU

union UH { unsigned int u; h2v h; fp16x2 p; };
__device__ __forceinline__ h2v uh(unsigned int u) { UH v; v.u = u; return v.h; }
__device__ __forceinline__ unsigned int hu(h2v h) { UH v; v.h = h; return v.u; }
#define BLO(w) __builtin_shufflevector(w, w, 0, 0)
#define BHI(w) __builtin_shufflevector(w, w, 1, 1)

__device__ __forceinline__ unsigned int pkrtz(float a, float b) {
    UH v; v.p = __builtin_amdgcn_cvt_pkrtz(a, b); return v.u;
}
__device__ __forceinline__ unsigned short f2hu(float f) {
    union { __half h; unsigned short u; } v; v.h = __float2half(f); return v.u;
}
__device__ __forceinline__ float fget(const float4& v, int e) {
    return e == 0 ? v.x : e == 1 ? v.y : e == 2 ? v.z : v.w;
}

// Tiny prep kernel.
// blocks 0..223: w2b96[row'][96] = f16([w2 | b2 | 0..]) with SLOT-PERMUTED rows:
//   row' = c8*448 + g*56 + ki*8 + kj (kj==7 rows zeroed) <-> w2 row (c8*8+g)*49 + ki*7 + kj
// block 224: w1h[m][c] = f16(w1[m][c] * sc[m])  (BN scale folded into w1),
//            sh2[m] = beta - mean*sc + b1*sc    (BN shift + bias, applied post-MFMA)
__global__ __launch_bounds__(256) void kprep(
    const float* __restrict__ w1, const float* __restrict__ b1,
    const float* __restrict__ gamma, const float* __restrict__ beta,
    const float* __restrict__ mean, const float* __restrict__ var,
    const float* __restrict__ w2, const float* __restrict__ b2,
    unsigned short* __restrict__ w2b96, unsigned short* __restrict__ w1h,
    float* __restrict__ sh2)
{
    const int t = threadIdx.x, bid = blockIdx.x;
    if (bid == 224) {
#pragma unroll
        for (int i = 0; i < 64; ++i) {
            int j = i * 256 + t;               // 16384 = 64 rows * 256 cols
            int row = j >> 8;
            float sc = gamma[row] * rsqrtf(var[row] + 1e-5f);
            w1h[j] = f2hu(w1[j] * sc);
        }
        if (t < 64) {
            float sc = gamma[t] * rsqrtf(var[t] + 1e-5f);
            sh2[t] = beta[t] - mean[t] * sc + b1[t] * sc;
        }
        return;
    }
    const int r0 = bid * 16;
#pragma unroll
    for (int i = 0; i < 6; ++i) {
        int j = i * 256 + t;                   // 1536 = 16 rows * 96
        int row = r0 + j / 96, col = j - (j / 96) * 96;
        int c8 = row / 448, rem = row - c8 * 448;
        int g = rem / 56, s = rem - g * 56;
        int ki = s >> 3, kj = s & 7;
        float v = 0.f;
        if (kj < 7) {
            int o = (c8 * 8 + g) * 49 + ki * 7 + kj;
            v = col < 64 ? w2[o * 64 + col] : (col == 64 ? b2[o] : 0.f);
        }
        w2b96[row * 96 + col] = f2hu(v);
    }
}

// Fully fused main kernel. One (batch, 8-group chunk) per block; 2x8 pixel tile.
// Phases: A stage (xt 256ch f16, xsb halo, yb tail) | B y-GEMM (K=256, BN folded)
//         | C wgen (K=96 MFMA, linear ds_write) | D involution.
// LDS 27136 B (wgt region aliased over xt) -> 6 blocks/CU.
__global__ __launch_bounds__(256, 6) void kmain(
    const float* __restrict__ x, const unsigned short* __restrict__ w2b96,
    const unsigned short* __restrict__ w1h, const float* __restrict__ sh2,
    float* __restrict__ out)
{
    __shared__ __align__(16) unsigned int smem_u[SMEM_W];
    unsigned short* wgt16 = (unsigned short*)smem_u;              // region A
    unsigned short* xt = (unsigned short*)smem_u;                 // aliases A: [16][264]
    unsigned int* xsb = smem_u + WGT_W;
    unsigned short* yb = (unsigned short*)(smem_u + WGT_W + XSB_W);  // [16][96]

    const int t = threadIdx.x;
    const int pix = t & 15, sub = t >> 4;
    const int lane = t & 63, wave = t >> 6;
    const int bc = blockIdx.x;
    const int b = bc >> 3, c8 = bc & 7;       // channels c8*32 .. +31 (8 groups)
    const int w0 = blockIdx.y * 8, h0 = blockIdx.z * 2;
    const int ph = pix >> 3, pw = pix & 7;    // 2 rows x 8 cols
    const int h = h0 + ph, w = w0 + pw;
    const int n = lane & 15, quad = lane >> 4;

    // A1: stage y-pixel x tile: 256 ch x 16 px fp32 -> f16 xt[px][ch] (stride 264)
    const float* xb = x + (size_t)b * 256 * HW;
#pragma unroll
    for (int i = 0; i < 4; ++i) {
        int j = i * 256 + t;                   // 1024 jobs: (c, pixel-quad)
        int c = j >> 2, pq = j & 3;
        int row = h0 + (pq >> 1), col = w0 + (pq & 1) * 4;
        float4 v = *(const float4*)(xb + (size_t)c * HW + row * 56 + col);
        int p = (pq >> 1) * 8 + (pq & 1) * 4;  // px = ph*8+pw ordering
        xt[(p + 0) * 264 + c] = f2hu(v.x);
        xt[(p + 1) * 264 + c] = f2hu(v.y);
        xt[(p + 2) * 264 + c] = f2hu(v.z);
        xt[(p + 3) * 264 + c] = f2hu(v.w);
    }

    // A2: stage x halo footprint: seg=(g,cp) x 8 rows; cols w0-3..w0+10, (ch0,ch1) packed.
    if (t < 128) {
        const int seg = t & 15, jr = t >> 4;
        const int jg = seg >> 1, jcp = seg & 1;
        const int hh = h0 + jr - 3;
        const bool rowok = (hh >= 0) && (hh < 56);
        const float* src = xb + ((size_t)c8 * 32 + jg * 4 + jcp * 2) * HW + hh * 56;
        float4 va[2][4];
#pragma unroll
        for (int q = 0; q < 4; ++q) {
            int col0 = w0 - 4 + q * 4;
            bool ok = rowok && (col0 >= 0) && (col0 <= 52);
#pragma unroll
            for (int ci = 0; ci < 2; ++ci)
                va[ci][q] = ok ? *(const float4*)(src + ci * HW + col0)
                              : make_float4(0.f, 0.f, 0.f, 0.f);
        }
        unsigned int* dst = xsb + seg * XSEG + jr * XROW;
#pragma unroll
        for (int q = 0; q < 4; ++q)
#pragma unroll
            for (int e = 0; e < 4; ++e) {
                int c = q * 4 + e - 1;               // col index w0-3+c
                if (c >= 0 && c < 14)
                    dst[c] = pkrtz(fget(va[0][q], e), fget(va[1][q], e));
            }
    }

    // A3: constant tail of yb rows: [64]=1.0h (bias lane), [65..95]=0
    if (t < 16) {
        unsigned short* yr = yb + t * 96 + 64;
        ushort4 one; one.x = 0x3C00u; one.y = 0; one.z = 0; one.w = 0;
        ushort4 z; z.x = 0; z.y = 0; z.z = 0; z.w = 0;
        *(ushort4*)(yr) = one;
#pragma unroll
        for (int q = 1; q < 8; ++q) *(ushort4*)(yr + q * 4) = z;
    }
    __syncthreads();

    // B: y-GEMM: wave computes ch m0..m0+15 x 16 px, K=256; yb[px][ch] = relu(...+sh2)
    {
        const int m0 = wave * 16;
        f32x4 acc = {0.f, 0.f, 0.f, 0.f};
#pragma unroll
        for (int k = 0; k < 8; ++k) {
            h8 aw = *(const h8*)(w1h + (size_t)(m0 + n) * 256 + k * 32 + quad * 8);
            h8 bv = *(const h8*)(&xt[n * 264 + k * 32 + quad * 8]);
            acc = __builtin_amdgcn_mfma_f32_16x16x32_f16(aw, bv, acc, 0, 0, 0);
        }
        float4 shv = *(const float4*)(sh2 + m0 + quad * 4);
        uint2 pk;
        pk.x = pkrtz(fmaxf(acc[0] + shv.x, 0.f), fmaxf(acc[1] + shv.y, 0.f));
        pk.y = pkrtz(fmaxf(acc[2] + shv.z, 0.f), fmaxf(acc[3] + shv.w, 0.f));
        *(uint2*)(yb + n * 96 + m0 + quad * 4) = pk;
    }
    __syncthreads();    // yb ready; xt dead (wgt may now overwrite region A)

    // C: weight generation: 448 slot-rows (28 tiles, exactly 7/wave) x 16 px, K=96 MFMA.
    //    Output row index == LDS slot index -> linear packed ds_write_b64.
    {
        const unsigned short* yrp = yb + n * 96 + quad * 8;
        const h8 bf0 = *(const h8*)(yrp);
        const h8 bf1 = *(const h8*)(yrp + 32);
        const h8 bf2 = *(const h8*)(yrp + 64);
        const int c0 = c8 * 448;
        for (int tile = wave; tile < 28; tile += 4) {
            const unsigned short* ap = w2b96 + (size_t)(c0 + tile * 16 + n) * 96 + quad * 8;
            h8 af0 = *(const h8*)(ap);
            h8 af1 = *(const h8*)(ap + 32);
            h8 af2 = *(const h8*)(ap + 64);
            f32x4 acc = {0.f, 0.f, 0.f, 0.f};
            acc = __builtin_amdgcn_mfma_f32_16x16x32_f16(af0, bf0, acc, 0, 0, 0);
            acc = __builtin_amdgcn_mfma_f32_16x16x32_f16(af1, bf1, acc, 0, 0, 0);
            acc = __builtin_amdgcn_mfma_f32_16x16x32_f16(af2, bf2, acc, 0, 0, 0);
            uint2 pk2;
            pk2.x = pkrtz(acc[0], acc[1]);
            pk2.y = pkrtz(acc[2], acc[3]);
            *(uint2*)(wgt16 + n * PS2 + tile * 16 + quad * 4) = pk2;
        }
    }
    __syncthreads();    // xsb + wgt ready

    // D: involution: thread = (pixel pix, group g, channel-pair cp)
    //    native v2f16 -> v_pk_fma_f16 with op_sel-folded broadcasts.
    const int g = sub & 7, cp = sub >> 3;
    const unsigned short* wr16 = wgt16 + pix * PS2 + g * 56;
    const unsigned int* xr = xsb + (g * 2 + cp) * XSEG + ph * XROW + pw;
    h2v acA = {(_Float16)0.f, (_Float16)0.f};
    h2v acB = acA;
#pragma unroll
    for (int ki = 0; ki < 7; ++ki) {
        uint4 wq = *(const uint4*)(wr16 + ki * 8);
        const unsigned int* xrow = xr + ki * XROW;
        unsigned int xv[7];
#pragma unroll
        for (int j = 0; j < 7; ++j) xv[j] = xrow[j];
        h2v w01 = uh(wq.x), w23 = uh(wq.y), w45 = uh(wq.z), w6p = uh(wq.w);
        acA += BLO(w01) * uh(xv[0]);
        acB += BHI(w01) * uh(xv[1]);
        acA += BLO(w23) * uh(xv[2]);
        acB += BHI(w23) * uh(xv[3]);
        acA += BLO(w45) * uh(xv[4]);
        acB += BHI(w45) * uh(xv[5]);
        acA += BLO(w6p) * uh(xv[6]);
    }
    h2v acc2 = acA + acB;
    float a0 = (float)acc2[0];
    float a1 = (float)acc2[1];

    size_t ob = ((size_t)b * 256 + c8 * 32 + g * 4 + cp * 2) * HW + h * 56 + w;
    out[ob] = a0;
    out[ob + HW] = a1;
}

extern "C" void kernel_launch(void* const* d_in, const int* in_sizes, int n_in,
                              void* d_out, int out_size, void* d_ws, size_t ws_size,
                              hipStream_t stream) {
    const float* x     = (const float*)d_in[0];
    const float* w1    = (const float*)d_in[1];
    const float* b1    = (const float*)d_in[2];
    const float* gamma = (const float*)d_in[3];
    const float* beta  = (const float*)d_in[4];
    const float* mean  = (const float*)d_in[5];
    const float* var   = (const float*)d_in[6];
    const float* w2    = (const float*)d_in[7];
    const float* b2    = (const float*)d_in[8];
    float* out = (float*)d_out;

    unsigned short* w2b96 = (unsigned short*)d_ws;         // 3584*96 u16
    unsigned short* w1h   = w2b96 + (size_t)3584 * 96;     // 64*256 u16
    float* sh2            = (float*)(w1h + 16384);         // 64 f32

    hipLaunchKernelGGL(kprep, dim3(225), dim3(256), 0, stream,
                       w1, b1, gamma, beta, mean, var, w2, b2, w2b96, w1h, sh2);
    hipLaunchKernelGGL(kmain, dim3(32, 7, 28), dim3(256), 0, stream,
                       x, w2b96, w1h, sh2, out);
}

// Round 6
// 147.633 us; speedup vs baseline: 1.0845x; 1.0845x over previous
//
#include <hip/hip_runtime.h>
#include <hip/hip_fp16.h>

typedef _Float16 h8 __attribute__((ext_vector_type(8)));
typedef _Float16 h2v __attribute__((ext_vector_type(2)));
typedef __fp16 fp16x2 __attribute__((ext_vector_type(2)));
typedef float f32x4 __attribute__((ext_vector_type(4)));

#define HW 3136    // 56*56
#define NPX 12544  // B*HW
#define YSTR 96    // ytb row stride: 64 y + [1, 0..0] b2 lane
#define XROW 16    // xsb row stride (u32): with 2*XSEG%32==8, phase-D x reads are a
                   //   perfect 2x bank cover per wave (free)
#define XSEG 148   // xsb segment stride (u32)
#define PS2 456    // wgt pixel stride (u16): 448 slots + 8 pad; 912B, 16B-aligned
#define WGT_W 3648 // wgt region words (16 px * 228)
#define W2R 3584   // w2b96 rows: 64 groups * 56 slots (permuted, dead rows zeroed)

union UH { unsigned int u; h2v h; fp16x2 p; };
__device__ __forceinline__ h2v uh(unsigned int u) { UH v; v.u = u; return v.h; }
__device__ __forceinline__ unsigned int hu(h2v h) { UH v; v.h = h; return v.u; }
#define BLO(w) __builtin_shufflevector(w, w, 0, 0)
#define BHI(w) __builtin_shufflevector(w, w, 1, 1)

__device__ __forceinline__ unsigned int pkrtz(float a, float b) {
    UH v; v.p = __builtin_amdgcn_cvt_pkrtz(a, b); return v.u;
}
__device__ __forceinline__ unsigned short f2hu(float f) {
    union { __half h; unsigned short u; } v; v.h = __float2half(f); return v.u;
}
__device__ __forceinline__ float fget(const float4& v, int e) {
    return e == 0 ? v.x : e == 1 ? v.y : e == 2 ? v.z : v.w;
}

// Merged prep + y-GEMM (all f16).
// blocks 0..783: y = relu(bn(w1 @ x)) -> ytb[px][96]
// blocks 784..1007: w2b96[row'][96] = f16([w2 | b2 | 0..]) with SLOT-PERMUTED rows:
//   row' = c8*448 + g*56 + ki*8 + kj (kj==7 rows zeroed) <-> w2 row (c8*8+g)*49 + ki*7 + kj
__global__ __launch_bounds__(256) void kyw(
    const float* __restrict__ x, const float* __restrict__ w1,
    const float* __restrict__ b1, const float* __restrict__ gamma,
    const float* __restrict__ beta, const float* __restrict__ mean,
    const float* __restrict__ var, const float* __restrict__ w2,
    const float* __restrict__ b2, unsigned short* __restrict__ ytb,
    unsigned short* __restrict__ w2b96)
{
    __shared__ unsigned short xt[16 * 264];    // [px][ch], stride 264 (u32 view: 132)
    const int t = threadIdx.x, bid = blockIdx.x;

    if (bid >= 784) {                          // w2 -> f16 K=96 rows, permuted
        const int r0 = (bid - 784) * 16;
#pragma unroll
        for (int i = 0; i < 6; ++i) {
            int j = i * 256 + t;               // 1536 = 16 rows * 96
            int row = r0 + j / 96, col = j - (j / 96) * 96;
            int c8 = row / 448, rem = row - c8 * 448;
            int g = rem / 56, s = rem - g * 56;
            int ki = s >> 3, kj = s & 7;
            float v = 0.f;
            if (kj < 7) {
                int o = (c8 * 8 + g) * 49 + ki * 7 + kj;
                v = col < 64 ? w2[o * 64 + col] : (col == 64 ? b2[o] : 0.f);
            }
            w2b96[row * 96 + col] = f2hu(v);
        }
        return;
    }

    const int px0 = bid * 16;
    const int b = px0 / HW;
    const int p0 = px0 - b * HW;

    // stage x tile: 256 ch x 16 px fp32 -> f16 xt[px][ch]; channel-PAIR packed
    // writes (pkrtz + ds_write_b32, 2-way banks = free).
    {
        unsigned int* xw = (unsigned int*)xt;
#pragma unroll
        for (int i = 0; i < 2; ++i) {
            int j = i * 256 + t;               // 512 jobs: (cpair, pixel-quad)
            int cp2 = j >> 2, pq = j & 3;      // channels 2*cp2, 2*cp2+1
            const float* s0 = x + (size_t)(b * 256 + cp2 * 2) * HW + p0 + pq * 4;
            float4 v0 = *(const float4*)(s0);
            float4 v1 = *(const float4*)(s0 + HW);
            xw[(pq * 4 + 0) * 132 + cp2] = pkrtz(v0.x, v1.x);
            xw[(pq * 4 + 1) * 132 + cp2] = pkrtz(v0.y, v1.y);
            xw[(pq * 4 + 2) * 132 + cp2] = pkrtz(v0.z, v1.z);
            xw[(pq * 4 + 3) * 132 + cp2] = pkrtz(v0.w, v1.w);
        }
    }
    // constant tail of ytb rows: [64]=1.0h (bias lane), [65..95]=0
    if (t < 16) {
        unsigned short* yr = ytb + (size_t)(px0 + t) * YSTR + 64;
        ushort4 one; one.x = 0x3C00u; one.y = 0; one.z = 0; one.w = 0;
        ushort4 z; z.x = 0; z.y = 0; z.z = 0; z.w = 0;
        *(ushort4*)(yr) = one;
#pragma unroll
        for (int q = 1; q < 8; ++q) *(ushort4*)(yr + q * 4) = z;
    }
    __syncthreads();

    const int lane = t & 63, wave = t >> 6;
    const int n = lane & 15, quad = lane >> 4;
    const int m0 = wave * 16;

    f32x4 acc = {0.f, 0.f, 0.f, 0.f};
#pragma unroll
    for (int k = 0; k < 8; ++k) {
        const float* wrow = w1 + (m0 + n) * 256 + k * 32 + quad * 8;
        float4 wa = *(const float4*)(wrow);
        float4 wb = *(const float4*)(wrow + 4);
        union { uint4 u; h8 h; } A;
        A.u.x = pkrtz(wa.x, wa.y);
        A.u.y = pkrtz(wa.z, wa.w);
        A.u.z = pkrtz(wb.x, wb.y);
        A.u.w = pkrtz(wb.z, wb.w);
        h8 bfv = *(const h8*)(&xt[n * 264 + k * 32 + quad * 8]);
        acc = __builtin_amdgcn_mfma_f32_16x16x32_f16(A.h, bfv, acc, 0, 0, 0);
    }
    float pv[4];
#pragma unroll
    for (int r = 0; r < 4; ++r) {
        int m = m0 + quad * 4 + r;
        float sc = gamma[m] * rsqrtf(var[m] + 1e-5f);
        float sh = beta[m] - mean[m] * sc + b1[m] * sc;
        pv[r] = fmaxf(acc[r] * sc + sh, 0.f);
    }
    uint2 pk;
    pk.x = pkrtz(pv[0], pv[1]);
    pk.y = pkrtz(pv[2], pv[3]);
    *(uint2*)(ytb + (size_t)(px0 + n) * YSTR + m0 + quad * 4) = pk;
}

// One (batch, 8-group chunk) per block; 2x8 pixel tile.
// LDS 24064 B -> 6 blocks/CU. grid (32, 7, 28).
// Phase C: software-pipelined (load tile t+1 fragments during tile t MFMAs).
// Phase D: all 7 weight quads preloaded (ds_read_b128 back-to-back), then FMAs.
__global__ __launch_bounds__(256, 6) void kmain(
    const float* __restrict__ x, const unsigned short* __restrict__ w2b96,
    const unsigned short* __restrict__ ytb, float* __restrict__ out)
{
    __shared__ __align__(16) unsigned int smem_u[WGT_W + 16 * XSEG];  // 24064 B
    unsigned short* wgt16 = (unsigned short*)smem_u;
    unsigned int* xsb = smem_u + WGT_W;

    const int t = threadIdx.x;
    const int pix = t & 15, sub = t >> 4;
    const int lane = t & 63, wave = t >> 6;
    const int bc = blockIdx.x;
    const int b = bc >> 3, c8 = bc & 7;       // channels c8*32 .. +31 (8 groups)
    const int w0 = blockIdx.y * 8, h0 = blockIdx.z * 2;
    const int ph = pix >> 3, pw = pix & 7;    // 2 rows x 8 cols
    const int h = h0 + ph, w = w0 + pw;
    const int n = lane & 15, quad = lane >> 4;

    // A: B-fragments from ytb first (longest-latency loads, needed for w-gen)
    const int Pn = b * HW + (h0 + (n >> 3)) * 56 + w0 + (n & 7);
    const unsigned short* yrp = ytb + (size_t)Pn * YSTR + quad * 8;
    const h8 bf0 = *(const h8*)(yrp);
    const h8 bf1 = *(const h8*)(yrp + 32);
    const h8 bf2 = *(const h8*)(yrp + 64);

    // B: stage x halo footprint: seg=(g,cp) x 8 rows; cols w0-3..w0+10, (ch0,ch1) packed.
    if (t < 128) {
        const int seg = t & 15, jr = t >> 4;
        const int jg = seg >> 1, jcp = seg & 1;
        const int hh = h0 + jr - 3;
        const bool rowok = (hh >= 0) && (hh < 56);
        const float* src = x + ((size_t)b * 256 + c8 * 32 + jg * 4 + jcp * 2) * HW + hh * 56;
        float4 va[2][4];
#pragma unroll
        for (int q = 0; q < 4; ++q) {
            int col0 = w0 - 4 + q * 4;
            bool ok = rowok && (col0 >= 0) && (col0 <= 52);
#pragma unroll
            for (int ci = 0; ci < 2; ++ci)
                va[ci][q] = ok ? *(const float4*)(src + ci * HW + col0)
                              : make_float4(0.f, 0.f, 0.f, 0.f);
        }
        unsigned int* dst = xsb + seg * XSEG + jr * XROW;
#pragma unroll
        for (int q = 0; q < 4; ++q)
#pragma unroll
            for (int e = 0; e < 4; ++e) {
                int c = q * 4 + e - 1;               // col index w0-3+c
                if (c >= 0 && c < 14)
                    dst[c] = pkrtz(fget(va[0][q], e), fget(va[1][q], e));
            }
    }

    // C: weight generation: 448 slot-rows (28 tiles, exactly 7/wave) x 16 px, K=96 MFMA.
    //    Output row index == LDS slot index -> linear packed ds_write_b64.
    //    Double-buffered: next tile's 3 A-fragments load during current MFMAs.
    {
        const int c0 = c8 * 448;
        const unsigned short* ap = w2b96 + (size_t)(c0 + wave * 16 + n) * 96 + quad * 8;
        h8 a0 = *(const h8*)(ap);
        h8 a1 = *(const h8*)(ap + 32);
        h8 a2 = *(const h8*)(ap + 64);
#pragma unroll
        for (int tt = 0; tt < 7; ++tt) {
            h8 b0 = a0, b1 = a1, b2 = a2;
            if (tt < 6) {
                const unsigned short* np = ap + (size_t)(tt + 1) * 6144;  // 64 rows * 96
                b0 = *(const h8*)(np);
                b1 = *(const h8*)(np + 32);
                b2 = *(const h8*)(np + 64);
            }
            f32x4 acc = {0.f, 0.f, 0.f, 0.f};
            acc = __builtin_amdgcn_mfma_f32_16x16x32_f16(a0, bf0, acc, 0, 0, 0);
            acc = __builtin_amdgcn_mfma_f32_16x16x32_f16(a1, bf1, acc, 0, 0, 0);
            acc = __builtin_amdgcn_mfma_f32_16x16x32_f16(a2, bf2, acc, 0, 0, 0);
            uint2 pk2;
            pk2.x = pkrtz(acc[0], acc[1]);
            pk2.y = pkrtz(acc[2], acc[3]);
            *(uint2*)(wgt16 + n * PS2 + (wave + 4 * tt) * 16 + quad * 4) = pk2;
            a0 = b0; a1 = b1; a2 = b2;
        }
    }
    __syncthreads();    // the only barrier: xsb + wgt ready

    // D: involution: thread = (pixel pix, group g, channel-pair cp)
    //    weight quads preloaded; native v2f16 -> v_pk_fma_f16, op_sel broadcasts.
    const int g = sub & 7, cp = sub >> 3;
    const unsigned short* wr16 = wgt16 + pix * PS2 + g * 56;
    const unsigned int* xr = xsb + (g * 2 + cp) * XSEG + ph * XROW + pw;
    uint4 wq[7];
#pragma unroll
    for (int ki = 0; ki < 7; ++ki) wq[ki] = *(const uint4*)(wr16 + ki * 8);
    h2v acA = {(_Float16)0.f, (_Float16)0.f};
    h2v acB = acA;
#pragma unroll
    for (int ki = 0; ki < 7; ++ki) {
        const unsigned int* xrow = xr + ki * XROW;
        unsigned int xv[7];
#pragma unroll
        for (int j = 0; j < 7; ++j) xv[j] = xrow[j];
        h2v w01 = uh(wq[ki].x), w23 = uh(wq[ki].y), w45 = uh(wq[ki].z), w6p = uh(wq[ki].w);
        acA += BLO(w01) * uh(xv[0]);
        acB += BHI(w01) * uh(xv[1]);
        acA += BLO(w23) * uh(xv[2]);
        acB += BHI(w23) * uh(xv[3]);
        acA += BLO(w45) * uh(xv[4]);
        acB += BHI(w45) * uh(xv[5]);
        acA += BLO(w6p) * uh(xv[6]);
    }
    h2v acc2 = acA + acB;
    float a0 = (float)acc2[0];
    float a1 = (float)acc2[1];

    size_t ob = ((size_t)b * 256 + c8 * 32 + g * 4 + cp * 2) * HW + h * 56 + w;
    out[ob] = a0;
    out[ob + HW] = a1;
}

extern "C" void kernel_launch(void* const* d_in, const int* in_sizes, int n_in,
                              void* d_out, int out_size, void* d_ws, size_t ws_size,
                              hipStream_t stream) {
    const float* x     = (const float*)d_in[0];
    const float* w1    = (const float*)d_in[1];
    const float* b1    = (const float*)d_in[2];
    const float* gamma = (const float*)d_in[3];
    const float* beta  = (const float*)d_in[4];
    const float* mean  = (const float*)d_in[5];
    const float* var   = (const float*)d_in[6];
    const float* w2    = (const float*)d_in[7];
    const float* b2    = (const float*)d_in[8];
    float* out = (float*)d_out;

    unsigned short* ytb   = (unsigned short*)d_ws;         // 12544*96 u16
    unsigned short* w2b96 = ytb + (size_t)NPX * YSTR;      // 3584*96 u16 (permuted rows)
    hipLaunchKernelGGL(kyw, dim3(1008), dim3(256), 0, stream,
                       x, w1, b1, gamma, beta, mean, var, w2, b2, ytb, w2b96);
    hipLaunchKernelGGL(kmain, dim3(32, 7, 28), dim3(256), 0, stream,
                       x, w2b96, ytb, out);
}

// Round 7
// 134.045 us; speedup vs baseline: 1.1945x; 1.1014x over previous
//
#include <hip/hip_runtime.h>
#include <hip/hip_fp16.h>

typedef _Float16 h8 __attribute__((ext_vector_type(8)));
typedef _Float16 h2v __attribute__((ext_vector_type(2)));
typedef __fp16 fp16x2 __attribute__((ext_vector_type(2)));
typedef float f32x4 __attribute__((ext_vector_type(4)));

#define HW 3136    // 56*56
#define NPX 12544  // B*HW
#define YSTR 96    // ytb row stride: 64 y + [1, 0..0] b2 lane
#define XROW 16    // xsb row stride (u32): with 2*XSEG%32==8, phase-D x reads are a
                   //   perfect 2x bank cover per wave (free)
#define XSEG 148   // xsb segment stride (u32)
#define PS2 456    // wgt pixel stride (u16): 448 slots + 8 pad; 912B, 16B-aligned
#define WGT_W 3648 // wgt region words (16 px * 228)

union UH { unsigned int u; h2v h; fp16x2 p; };
__device__ __forceinline__ h2v uh(unsigned int u) { UH v; v.u = u; return v.h; }
__device__ __forceinline__ unsigned int hu(h2v h) { UH v; v.h = h; return v.u; }
#define BLO(w) __builtin_shufflevector(w, w, 0, 0)
#define BHI(w) __builtin_shufflevector(w, w, 1, 1)

__device__ __forceinline__ unsigned int pkrtz(float a, float b) {
    UH v; v.p = __builtin_amdgcn_cvt_pkrtz(a, b); return v.u;
}
__device__ __forceinline__ unsigned short f2hu(float f) {
    union { __half h; unsigned short u; } v; v.h = __float2half(f); return v.u;
}
__device__ __forceinline__ float fget(const float4& v, int e) {
    return e == 0 ? v.x : e == 1 ? v.y : e == 2 ? v.z : v.w;
}

// Merged prep + y-GEMM (all f16).
// blocks 0..195: y = relu(bn(w1 @ x)) for 64 px each -> ytb[px][96]
//   (w1 converted ONCE per block, reused across 4 pixel sub-tiles)
// blocks 196..419: w2b96[row'][96] = f16([w2 | b2 | 0..]) with SLOT-PERMUTED rows:
//   row' = c8*448 + g*56 + ki*8 + kj (kj==7 rows zeroed) <-> w2 row (c8*8+g)*49 + ki*7 + kj
__global__ __launch_bounds__(256) void kyw(
    const float* __restrict__ x, const float* __restrict__ w1,
    const float* __restrict__ b1, const float* __restrict__ gamma,
    const float* __restrict__ beta, const float* __restrict__ mean,
    const float* __restrict__ var, const float* __restrict__ w2,
    const float* __restrict__ b2, unsigned short* __restrict__ ytb,
    unsigned short* __restrict__ w2b96)
{
    __shared__ unsigned short xt[64 * 264];    // [px][ch], stride 264 (u32 view: 132)
    const int t = threadIdx.x, bid = blockIdx.x;

    if (bid >= 196) {                          // w2 -> f16 K=96 rows, permuted
        const int r0 = (bid - 196) * 16;
#pragma unroll
        for (int i = 0; i < 6; ++i) {
            int j = i * 256 + t;               // 1536 = 16 rows * 96
            int row = r0 + j / 96, col = j - (j / 96) * 96;
            int c8 = row / 448, rem = row - c8 * 448;
            int g = rem / 56, s = rem - g * 56;
            int ki = s >> 3, kj = s & 7;
            float v = 0.f;
            if (kj < 7) {
                int o = (c8 * 8 + g) * 49 + ki * 7 + kj;
                v = col < 64 ? w2[o * 64 + col] : (col == 64 ? b2[o] : 0.f);
            }
            w2b96[row * 96 + col] = f2hu(v);
        }
        return;
    }

    const int px0 = bid * 64;
    const int b = px0 / HW;
    const int p0 = px0 - b * HW;               // multiple of 64 (3136 % 64 == 0)

    // stage x tile: 256 ch x 64 px fp32 -> f16 xt[px][ch], channel-PAIR packed.
    // 4 passes of the proven 16-px pattern: 256B-chunk coalesced loads,
    // 2-way (free) LDS write banks.
    {
        unsigned int* xw = (unsigned int*)xt;
#pragma unroll
        for (int s = 0; s < 4; ++s)
#pragma unroll
            for (int i = 0; i < 2; ++i) {
                int j = i * 256 + t;           // 512 jobs: (cpair, pixel-quad)
                int cp2 = j >> 2, pq = j & 3;  // channels 2*cp2, 2*cp2+1
                const float* s0 = x + (size_t)(b * 256 + cp2 * 2) * HW
                                    + p0 + s * 16 + pq * 4;
                float4 v0 = *(const float4*)(s0);
                float4 v1 = *(const float4*)(s0 + HW);
                int pxb = s * 16 + pq * 4;
                xw[(pxb + 0) * 132 + cp2] = pkrtz(v0.x, v1.x);
                xw[(pxb + 1) * 132 + cp2] = pkrtz(v0.y, v1.y);
                xw[(pxb + 2) * 132 + cp2] = pkrtz(v0.z, v1.z);
                xw[(pxb + 3) * 132 + cp2] = pkrtz(v0.w, v1.w);
            }
    }
    // constant tail of ytb rows: [64]=1.0h (bias lane), [65..95]=0
    if (t < 64) {
        unsigned short* yr = ytb + (size_t)(px0 + t) * YSTR + 64;
        ushort4 one; one.x = 0x3C00u; one.y = 0; one.z = 0; one.w = 0;
        ushort4 z; z.x = 0; z.y = 0; z.z = 0; z.w = 0;
        *(ushort4*)(yr) = one;
#pragma unroll
        for (int q = 1; q < 8; ++q) *(ushort4*)(yr + q * 4) = z;
    }
    __syncthreads();

    const int lane = t & 63, wave = t >> 6;
    const int n = lane & 15, quad = lane >> 4;
    const int m0 = wave * 16;

    // w1 -> f16 A-fragments ONCE per block (amortized over 4 px sub-tiles)
    h8 A[8];
#pragma unroll
    for (int k = 0; k < 8; ++k) {
        const float* wrow = w1 + (m0 + n) * 256 + k * 32 + quad * 8;
        float4 wa = *(const float4*)(wrow);
        float4 wb = *(const float4*)(wrow + 4);
        union { uint4 u; h8 h; } Au;
        Au.u.x = pkrtz(wa.x, wa.y);
        Au.u.y = pkrtz(wa.z, wa.w);
        Au.u.z = pkrtz(wb.x, wb.y);
        Au.u.w = pkrtz(wb.z, wb.w);
        A[k] = Au.h;
    }
    float sc[4], sh[4];
#pragma unroll
    for (int r = 0; r < 4; ++r) {
        int m = m0 + quad * 4 + r;
        sc[r] = gamma[m] * rsqrtf(var[m] + 1e-5f);
        sh[r] = beta[m] - mean[m] * sc[r] + b1[m] * sc[r];
    }

#pragma unroll
    for (int s = 0; s < 4; ++s) {
        f32x4 acc = {0.f, 0.f, 0.f, 0.f};
#pragma unroll
        for (int k = 0; k < 8; ++k) {
            h8 bv = *(const h8*)(&xt[(s * 16 + n) * 264 + k * 32 + quad * 8]);
            acc = __builtin_amdgcn_mfma_f32_16x16x32_f16(A[k], bv, acc, 0, 0, 0);
        }
        uint2 pk;
        pk.x = pkrtz(fmaxf(acc[0] * sc[0] + sh[0], 0.f),
                     fmaxf(acc[1] * sc[1] + sh[1], 0.f));
        pk.y = pkrtz(fmaxf(acc[2] * sc[2] + sh[2], 0.f),
                     fmaxf(acc[3] * sc[3] + sh[3], 0.f));
        *(uint2*)(ytb + (size_t)(px0 + s * 16 + n) * YSTR + m0 + quad * 4) = pk;
    }
}

// One (batch, 8-group chunk) per block; 2x8 pixel tile.  [identical to R4: 56.7 us]
// LDS 24064 B -> 6 blocks/CU. grid (32, 7, 28).
__global__ __launch_bounds__(256, 6) void kmain(
    const float* __restrict__ x, const unsigned short* __restrict__ w2b96,
    const unsigned short* __restrict__ ytb, float* __restrict__ out)
{
    __shared__ __align__(16) unsigned int smem_u[WGT_W + 16 * XSEG];  // 24064 B
    unsigned short* wgt16 = (unsigned short*)smem_u;
    unsigned int* xsb = smem_u + WGT_W;

    const int t = threadIdx.x;
    const int pix = t & 15, sub = t >> 4;
    const int lane = t & 63, wave = t >> 6;
    const int bc = blockIdx.x;
    const int b = bc >> 3, c8 = bc & 7;       // channels c8*32 .. +31 (8 groups)
    const int w0 = blockIdx.y * 8, h0 = blockIdx.z * 2;
    const int ph = pix >> 3, pw = pix & 7;    // 2 rows x 8 cols
    const int h = h0 + ph, w = w0 + pw;
    const int n = lane & 15, quad = lane >> 4;

    // A: B-fragments from ytb first (longest-latency loads, needed for w-gen)
    const int Pn = b * HW + (h0 + (n >> 3)) * 56 + w0 + (n & 7);
    const unsigned short* yrp = ytb + (size_t)Pn * YSTR + quad * 8;
    const h8 bf0 = *(const h8*)(yrp);
    const h8 bf1 = *(const h8*)(yrp + 32);
    const h8 bf2 = *(const h8*)(yrp + 64);

    // B: stage x halo footprint: seg=(g,cp) x 8 rows; cols w0-3..w0+10, (ch0,ch1) packed.
    if (t < 128) {
        const int seg = t & 15, jr = t >> 4;
        const int jg = seg >> 1, jcp = seg & 1;
        const int hh = h0 + jr - 3;
        const bool rowok = (hh >= 0) && (hh < 56);
        const float* src = x + ((size_t)b * 256 + c8 * 32 + jg * 4 + jcp * 2) * HW + hh * 56;
        float4 va[2][4];
#pragma unroll
        for (int q = 0; q < 4; ++q) {
            int col0 = w0 - 4 + q * 4;
            bool ok = rowok && (col0 >= 0) && (col0 <= 52);
#pragma unroll
            for (int ci = 0; ci < 2; ++ci)
                va[ci][q] = ok ? *(const float4*)(src + ci * HW + col0)
                              : make_float4(0.f, 0.f, 0.f, 0.f);
        }
        unsigned int* dst = xsb + seg * XSEG + jr * XROW;
#pragma unroll
        for (int q = 0; q < 4; ++q)
#pragma unroll
            for (int e = 0; e < 4; ++e) {
                int c = q * 4 + e - 1;               // col index w0-3+c
                if (c >= 0 && c < 14)
                    dst[c] = pkrtz(fget(va[0][q], e), fget(va[1][q], e));
            }
    }

    // C: weight generation: 448 slot-rows (28 tiles, exactly 7/wave) x 16 px, K=96 MFMA.
    //    Output row index == LDS slot index -> linear packed ds_write_b64.
    {
        const int c0 = c8 * 448;
        for (int tile = wave; tile < 28; tile += 4) {
            const unsigned short* ap = w2b96 + (size_t)(c0 + tile * 16 + n) * 96 + quad * 8;
            h8 af0 = *(const h8*)(ap);
            h8 af1 = *(const h8*)(ap + 32);
            h8 af2 = *(const h8*)(ap + 64);
            f32x4 acc = {0.f, 0.f, 0.f, 0.f};
            acc = __builtin_amdgcn_mfma_f32_16x16x32_f16(af0, bf0, acc, 0, 0, 0);
            acc = __builtin_amdgcn_mfma_f32_16x16x32_f16(af1, bf1, acc, 0, 0, 0);
            acc = __builtin_amdgcn_mfma_f32_16x16x32_f16(af2, bf2, acc, 0, 0, 0);
            uint2 pk2;
            pk2.x = pkrtz(acc[0], acc[1]);
            pk2.y = pkrtz(acc[2], acc[3]);
            *(uint2*)(wgt16 + n * PS2 + tile * 16 + quad * 4) = pk2;
        }
    }
    __syncthreads();    // the only barrier: xsb + wgt ready

    // D: involution: thread = (pixel pix, group g, channel-pair cp)
    //    native v2f16 -> v_pk_fma_f16 with op_sel-folded broadcasts.
    const int g = sub & 7, cp = sub >> 3;
    const unsigned short* wr16 = wgt16 + pix * PS2 + g * 56;
    const unsigned int* xr = xsb + (g * 2 + cp) * XSEG + ph * XROW + pw;
    h2v acA = {(_Float16)0.f, (_Float16)0.f};
    h2v acB = acA;
#pragma unroll
    for (int ki = 0; ki < 7; ++ki) {
        uint4 wq = *(const uint4*)(wr16 + ki * 8);
        const unsigned int* xrow = xr + ki * XROW;
        unsigned int xv[7];
#pragma unroll
        for (int j = 0; j < 7; ++j) xv[j] = xrow[j];
        h2v w01 = uh(wq.x), w23 = uh(wq.y), w45 = uh(wq.z), w6p = uh(wq.w);
        acA += BLO(w01) * uh(xv[0]);
        acB += BHI(w01) * uh(xv[1]);
        acA += BLO(w23) * uh(xv[2]);
        acB += BHI(w23) * uh(xv[3]);
        acA += BLO(w45) * uh(xv[4]);
        acB += BHI(w45) * uh(xv[5]);
        acA += BLO(w6p) * uh(xv[6]);
    }
    h2v acc2 = acA + acB;
    float a0 = (float)acc2[0];
    float a1 = (float)acc2[1];

    size_t ob = ((size_t)b * 256 + c8 * 32 + g * 4 + cp * 2) * HW + h * 56 + w;
    out[ob] = a0;
    out[ob + HW] = a1;
}

extern "C" void kernel_launch(void* const* d_in, const int* in_sizes, int n_in,
                              void* d_out, int out_size, void* d_ws, size_t ws_size,
                              hipStream_t stream) {
    const float* x     = (const float*)d_in[0];
    const float* w1    = (const float*)d_in[1];
    const float* b1    = (const float*)d_in[2];
    const float* gamma = (const float*)d_in[3];
    const float* beta  = (const float*)d_in[4];
    const float* mean  = (const float*)d_in[5];
    const float* var   = (const float*)d_in[6];
    const float* w2    = (const float*)d_in[7];
    const float* b2    = (const float*)d_in[8];
    float* out = (float*)d_out;

    unsigned short* ytb   = (unsigned short*)d_ws;         // 12544*96 u16
    unsigned short* w2b96 = ytb + (size_t)NPX * YSTR;      // 3584*96 u16 (permuted rows)
    hipLaunchKernelGGL(kyw, dim3(420), dim3(256), 0, stream,
                       x, w1, b1, gamma, beta, mean, var, w2, b2, ytb, w2b96);
    hipLaunchKernelGGL(kmain, dim3(32, 7, 28), dim3(256), 0, stream,
                       x, w2b96, ytb, out);
}

// Round 8
// 133.870 us; speedup vs baseline: 1.1960x; 1.0013x over previous
//
#include <hip/hip_runtime.h>
#include <hip/hip_fp16.h>

typedef _Float16 h8 __attribute__((ext_vector_type(8)));
typedef _Float16 h2v __attribute__((ext_vector_type(2)));
typedef __fp16 fp16x2 __attribute__((ext_vector_type(2)));
typedef float f32x4 __attribute__((ext_vector_type(4)));

#define HW 3136    // 56*56
#define NPX 12544  // B*HW
#define YSTR 96    // ytb row stride: 64 y + [1, 0..0] b2 lane
#define XROW 14    // xsb row stride (u32) == exactly the 14 used cols
#define XSEG 116   // xsb segment stride (u32): 8*14+4; 2*116 % 32 == 8 -> phase-D
                   //   x reads stay <=2-way per 32-lane group (free)
#define PS2 456    // wgt pixel stride (u16): 448 slots + 8 pad; 912B, 16B-aligned
#define WGT_W 3648 // wgt region words (16 px * 228)
// LDS total: 3648*4 + 16*116*4 = 14592 + 7424 = 22016 B -> 7 blocks/CU (28 waves)

union UH { unsigned int u; h2v h; fp16x2 p; };
__device__ __forceinline__ h2v uh(unsigned int u) { UH v; v.u = u; return v.h; }
__device__ __forceinline__ unsigned int hu(h2v h) { UH v; v.h = h; return v.u; }
#define BLO(w) __builtin_shufflevector(w, w, 0, 0)
#define BHI(w) __builtin_shufflevector(w, w, 1, 1)

__device__ __forceinline__ unsigned int pkrtz(float a, float b) {
    UH v; v.p = __builtin_amdgcn_cvt_pkrtz(a, b); return v.u;
}
__device__ __forceinline__ unsigned short f2hu(float f) {
    union { __half h; unsigned short u; } v; v.h = __float2half(f); return v.u;
}
__device__ __forceinline__ float fget(const float4& v, int e) {
    return e == 0 ? v.x : e == 1 ? v.y : e == 2 ? v.z : v.w;
}

// Merged prep + y-GEMM (all f16).
// blocks 0..195: y = relu(bn(w1 @ x)) for 64 px each -> ytb[px][96]
//   (w1 converted ONCE per block, reused across 4 pixel sub-tiles)
// blocks 196..419: w2b96[row'][96] = f16([w2 | b2 | 0..]) with SLOT-PERMUTED rows:
//   row' = c8*448 + g*56 + ki*8 + kj (kj==7 rows zeroed) <-> w2 row (c8*8+g)*49 + ki*7 + kj
__global__ __launch_bounds__(256) void kyw(
    const float* __restrict__ x, const float* __restrict__ w1,
    const float* __restrict__ b1, const float* __restrict__ gamma,
    const float* __restrict__ beta, const float* __restrict__ mean,
    const float* __restrict__ var, const float* __restrict__ w2,
    const float* __restrict__ b2, unsigned short* __restrict__ ytb,
    unsigned short* __restrict__ w2b96)
{
    __shared__ unsigned short xt[64 * 264];    // [px][ch], stride 264 (u32 view: 132)
    const int t = threadIdx.x, bid = blockIdx.x;

    if (bid >= 196) {                          // w2 -> f16 K=96 rows, permuted
        const int r0 = (bid - 196) * 16;
#pragma unroll
        for (int i = 0; i < 6; ++i) {
            int j = i * 256 + t;               // 1536 = 16 rows * 96
            int row = r0 + j / 96, col = j - (j / 96) * 96;
            int c8 = row / 448, rem = row - c8 * 448;
            int g = rem / 56, s = rem - g * 56;
            int ki = s >> 3, kj = s & 7;
            float v = 0.f;
            if (kj < 7) {
                int o = (c8 * 8 + g) * 49 + ki * 7 + kj;
                v = col < 64 ? w2[o * 64 + col] : (col == 64 ? b2[o] : 0.f);
            }
            w2b96[row * 96 + col] = f2hu(v);
        }
        return;
    }

    const int px0 = bid * 64;
    const int b = px0 / HW;
    const int p0 = px0 - b * HW;               // multiple of 64 (3136 % 64 == 0)

    // stage x tile: 256 ch x 64 px fp32 -> f16 xt[px][ch], channel-PAIR packed.
    {
        unsigned int* xw = (unsigned int*)xt;
#pragma unroll
        for (int s = 0; s < 4; ++s)
#pragma unroll
            for (int i = 0; i < 2; ++i) {
                int j = i * 256 + t;           // 512 jobs: (cpair, pixel-quad)
                int cp2 = j >> 2, pq = j & 3;  // channels 2*cp2, 2*cp2+1
                const float* s0 = x + (size_t)(b * 256 + cp2 * 2) * HW
                                    + p0 + s * 16 + pq * 4;
                float4 v0 = *(const float4*)(s0);
                float4 v1 = *(const float4*)(s0 + HW);
                int pxb = s * 16 + pq * 4;
                xw[(pxb + 0) * 132 + cp2] = pkrtz(v0.x, v1.x);
                xw[(pxb + 1) * 132 + cp2] = pkrtz(v0.y, v1.y);
                xw[(pxb + 2) * 132 + cp2] = pkrtz(v0.z, v1.z);
                xw[(pxb + 3) * 132 + cp2] = pkrtz(v0.w, v1.w);
            }
    }
    // constant tail of ytb rows: [64]=1.0h (bias lane), [65..95]=0
    if (t < 64) {
        unsigned short* yr = ytb + (size_t)(px0 + t) * YSTR + 64;
        ushort4 one; one.x = 0x3C00u; one.y = 0; one.z = 0; one.w = 0;
        ushort4 z; z.x = 0; z.y = 0; z.z = 0; z.w = 0;
        *(ushort4*)(yr) = one;
#pragma unroll
        for (int q = 1; q < 8; ++q) *(ushort4*)(yr + q * 4) = z;
    }
    __syncthreads();

    const int lane = t & 63, wave = t >> 6;
    const int n = lane & 15, quad = lane >> 4;
    const int m0 = wave * 16;

    // w1 -> f16 A-fragments ONCE per block (amortized over 4 px sub-tiles)
    h8 A[8];
#pragma unroll
    for (int k = 0; k < 8; ++k) {
        const float* wrow = w1 + (m0 + n) * 256 + k * 32 + quad * 8;
        float4 wa = *(const float4*)(wrow);
        float4 wb = *(const float4*)(wrow + 4);
        union { uint4 u; h8 h; } Au;
        Au.u.x = pkrtz(wa.x, wa.y);
        Au.u.y = pkrtz(wa.z, wa.w);
        Au.u.z = pkrtz(wb.x, wb.y);
        Au.u.w = pkrtz(wb.z, wb.w);
        A[k] = Au.h;
    }
    float sc[4], sh[4];
#pragma unroll
    for (int r = 0; r < 4; ++r) {
        int m = m0 + quad * 4 + r;
        sc[r] = gamma[m] * rsqrtf(var[m] + 1e-5f);
        sh[r] = beta[m] - mean[m] * sc[r] + b1[m] * sc[r];
    }

#pragma unroll
    for (int s = 0; s < 4; ++s) {
        f32x4 acc = {0.f, 0.f, 0.f, 0.f};
#pragma unroll
        for (int k = 0; k < 8; ++k) {
            h8 bv = *(const h8*)(&xt[(s * 16 + n) * 264 + k * 32 + quad * 8]);
            acc = __builtin_amdgcn_mfma_f32_16x16x32_f16(A[k], bv, acc, 0, 0, 0);
        }
        uint2 pk;
        pk.x = pkrtz(fmaxf(acc[0] * sc[0] + sh[0], 0.f),
                     fmaxf(acc[1] * sc[1] + sh[1], 0.f));
        pk.y = pkrtz(fmaxf(acc[2] * sc[2] + sh[2], 0.f),
                     fmaxf(acc[3] * sc[3] + sh[3], 0.f));
        *(uint2*)(ytb + (size_t)(px0 + s * 16 + n) * YSTR + m0 + quad * 4) = pk;
    }
}

// One (batch, 8-group chunk) per block; 2x8 pixel tile.
// LDS 22016 B -> 7 blocks/CU (28 waves, +17% latency hiding vs 24). grid (32, 7, 28).
__global__ __launch_bounds__(256, 7) void kmain(
    const float* __restrict__ x, const unsigned short* __restrict__ w2b96,
    const unsigned short* __restrict__ ytb, float* __restrict__ out)
{
    __shared__ __align__(16) unsigned int smem_u[WGT_W + 16 * XSEG];  // 22016 B
    unsigned short* wgt16 = (unsigned short*)smem_u;
    unsigned int* xsb = smem_u + WGT_W;

    const int t = threadIdx.x;
    const int pix = t & 15, sub = t >> 4;
    const int lane = t & 63, wave = t >> 6;
    const int bc = blockIdx.x;
    const int b = bc >> 3, c8 = bc & 7;       // channels c8*32 .. +31 (8 groups)
    const int w0 = blockIdx.y * 8, h0 = blockIdx.z * 2;
    const int ph = pix >> 3, pw = pix & 7;    // 2 rows x 8 cols
    const int h = h0 + ph, w = w0 + pw;
    const int n = lane & 15, quad = lane >> 4;

    // A: B-fragments from ytb first (longest-latency loads, needed for w-gen)
    const int Pn = b * HW + (h0 + (n >> 3)) * 56 + w0 + (n & 7);
    const unsigned short* yrp = ytb + (size_t)Pn * YSTR + quad * 8;
    const h8 bf0 = *(const h8*)(yrp);
    const h8 bf1 = *(const h8*)(yrp + 32);
    const h8 bf2 = *(const h8*)(yrp + 64);

    // B: stage x halo footprint: seg=(g,cp) x 8 rows; cols w0-3..w0+10, (ch0,ch1) packed.
    if (t < 128) {
        const int seg = t & 15, jr = t >> 4;
        const int jg = seg >> 1, jcp = seg & 1;
        const int hh = h0 + jr - 3;
        const bool rowok = (hh >= 0) && (hh < 56);
        const float* src = x + ((size_t)b * 256 + c8 * 32 + jg * 4 + jcp * 2) * HW + hh * 56;
        float4 va[2][4];
#pragma unroll
        for (int q = 0; q < 4; ++q) {
            int col0 = w0 - 4 + q * 4;
            bool ok = rowok && (col0 >= 0) && (col0 <= 52);
#pragma unroll
            for (int ci = 0; ci < 2; ++ci)
                va[ci][q] = ok ? *(const float4*)(src + ci * HW + col0)
                              : make_float4(0.f, 0.f, 0.f, 0.f);
        }
        unsigned int* dst = xsb + seg * XSEG + jr * XROW;
#pragma unroll
        for (int q = 0; q < 4; ++q)
#pragma unroll
            for (int e = 0; e < 4; ++e) {
                int c = q * 4 + e - 1;               // col index w0-3+c
                if (c >= 0 && c < 14)
                    dst[c] = pkrtz(fget(va[0][q], e), fget(va[1][q], e));
            }
    }

    // C: weight generation: 448 slot-rows (28 tiles, exactly 7/wave) x 16 px, K=96 MFMA.
    //    Output row index == LDS slot index -> linear packed ds_write_b64.
    {
        const int c0 = c8 * 448;
        for (int tile = wave; tile < 28; tile += 4) {
            const unsigned short* ap = w2b96 + (size_t)(c0 + tile * 16 + n) * 96 + quad * 8;
            h8 af0 = *(const h8*)(ap);
            h8 af1 = *(const h8*)(ap + 32);
            h8 af2 = *(const h8*)(ap + 64);
            f32x4 acc = {0.f, 0.f, 0.f, 0.f};
            acc = __builtin_amdgcn_mfma_f32_16x16x32_f16(af0, bf0, acc, 0, 0, 0);
            acc = __builtin_amdgcn_mfma_f32_16x16x32_f16(af1, bf1, acc, 0, 0, 0);
            acc = __builtin_amdgcn_mfma_f32_16x16x32_f16(af2, bf2, acc, 0, 0, 0);
            uint2 pk2;
            pk2.x = pkrtz(acc[0], acc[1]);
            pk2.y = pkrtz(acc[2], acc[3]);
            *(uint2*)(wgt16 + n * PS2 + tile * 16 + quad * 4) = pk2;
        }
    }
    __syncthreads();    // the only barrier: xsb + wgt ready

    // D: involution: thread = (pixel pix, group g, channel-pair cp)
    //    native v2f16 -> v_pk_fma_f16 with op_sel-folded broadcasts.
    const int g = sub & 7, cp = sub >> 3;
    const unsigned short* wr16 = wgt16 + pix * PS2 + g * 56;
    const unsigned int* xr = xsb + (g * 2 + cp) * XSEG + ph * XROW + pw;
    h2v acA = {(_Float16)0.f, (_Float16)0.f};
    h2v acB = acA;
#pragma unroll
    for (int ki = 0; ki < 7; ++ki) {
        uint4 wq = *(const uint4*)(wr16 + ki * 8);
        const unsigned int* xrow = xr + ki * XROW;
        unsigned int xv[7];
#pragma unroll
        for (int j = 0; j < 7; ++j) xv[j] = xrow[j];
        h2v w01 = uh(wq.x), w23 = uh(wq.y), w45 = uh(wq.z), w6p = uh(wq.w);
        acA += BLO(w01) * uh(xv[0]);
        acB += BHI(w01) * uh(xv[1]);
        acA += BLO(w23) * uh(xv[2]);
        acB += BHI(w23) * uh(xv[3]);
        acA += BLO(w45) * uh(xv[4]);
        acB += BHI(w45) * uh(xv[5]);
        acA += BLO(w6p) * uh(xv[6]);
    }
    h2v acc2 = acA + acB;
    float a0 = (float)acc2[0];
    float a1 = (float)acc2[1];

    size_t ob = ((size_t)b * 256 + c8 * 32 + g * 4 + cp * 2) * HW + h * 56 + w;
    out[ob] = a0;
    out[ob + HW] = a1;
}

extern "C" void kernel_launch(void* const* d_in, const int* in_sizes, int n_in,
                              void* d_out, int out_size, void* d_ws, size_t ws_size,
                              hipStream_t stream) {
    const float* x     = (const float*)d_in[0];
    const float* w1    = (const float*)d_in[1];
    const float* b1    = (const float*)d_in[2];
    const float* gamma = (const float*)d_in[3];
    const float* beta  = (const float*)d_in[4];
    const float* mean  = (const float*)d_in[5];
    const float* var   = (const float*)d_in[6];
    const float* w2    = (const float*)d_in[7];
    const float* b2    = (const float*)d_in[8];
    float* out = (float*)d_out;

    unsigned short* ytb   = (unsigned short*)d_ws;         // 12544*96 u16
    unsigned short* w2b96 = ytb + (size_t)NPX * YSTR;      // 3584*96 u16 (permuted rows)
    hipLaunchKernelGGL(kyw, dim3(420), dim3(256), 0, stream,
                       x, w1, b1, gamma, beta, mean, var, w2, b2, ytb, w2b96);
    hipLaunchKernelGGL(kmain, dim3(32, 7, 28), dim3(256), 0, stream,
                       x, w2b96, ytb, out);
}

// Round 9
// 121.681 us; speedup vs baseline: 1.3158x; 1.1002x over previous
//
#include <hip/hip_runtime.h>
#include <hip/hip_fp16.h>

typedef _Float16 h8 __attribute__((ext_vector_type(8)));
typedef _Float16 h2v __attribute__((ext_vector_type(2)));
typedef __fp16 fp16x2 __attribute__((ext_vector_type(2)));
typedef float f32x4 __attribute__((ext_vector_type(4)));

#define HW 3136    // 56*56
#define NPX 12544  // B*HW
#define YSTR 96    // ytb row stride: 64 y + [1, 0..0] b2 lane
#define XROW 14    // xsb row stride (u32)
#define XSEG 148   // xsb segment stride (u32): >=10*14; 2*148%32==8 -> phase-D x reads
                   //   are a per-half-wave bank permutation (free)
#define PS2 456    // wgt pixel stride (u16): 448 slots + 8 pad; 912B, 16B-aligned
#define WGT32_W 7296 // wgt region words: 32 px * 228
// LDS: 7296*4 + 16*148*4 = 29184 + 9472 = 38656 B -> 4 blocks/CU (16 waves)

union UH { unsigned int u; h2v h; fp16x2 p; };
__device__ __forceinline__ h2v uh(unsigned int u) { UH v; v.u = u; return v.h; }
__device__ __forceinline__ unsigned int hu(h2v h) { UH v; v.h = h; return v.u; }
#define BLO(w) __builtin_shufflevector(w, w, 0, 0)
#define BHI(w) __builtin_shufflevector(w, w, 1, 1)

__device__ __forceinline__ unsigned int pkrtz(float a, float b) {
    UH v; v.p = __builtin_amdgcn_cvt_pkrtz(a, b); return v.u;
}
__device__ __forceinline__ unsigned short f2hu(float f) {
    union { __half h; unsigned short u; } v; v.h = __float2half(f); return v.u;
}
__device__ __forceinline__ float fget(const float4& v, int e) {
    return e == 0 ? v.x : e == 1 ? v.y : e == 2 ? v.z : v.w;
}

// Merged prep + y-GEMM (all f16).  [unchanged from R7: ~8-9 us]
// blocks 0..195: y = relu(bn(w1 @ x)) for 64 px each -> ytb[px][96]
// blocks 196..419: w2b96[row'][96] = f16([w2 | b2 | 0..]) slot-permuted:
//   row' = c8*448 + g*56 + ki*8 + kj (kj==7 rows zeroed) <-> w2 row (c8*8+g)*49 + ki*7 + kj
__global__ __launch_bounds__(256) void kyw(
    const float* __restrict__ x, const float* __restrict__ w1,
    const float* __restrict__ b1, const float* __restrict__ gamma,
    const float* __restrict__ beta, const float* __restrict__ mean,
    const float* __restrict__ var, const float* __restrict__ w2,
    const float* __restrict__ b2, unsigned short* __restrict__ ytb,
    unsigned short* __restrict__ w2b96)
{
    __shared__ unsigned short xt[64 * 264];    // [px][ch], stride 264 (u32 view: 132)
    const int t = threadIdx.x, bid = blockIdx.x;

    if (bid >= 196) {                          // w2 -> f16 K=96 rows, permuted
        const int r0 = (bid - 196) * 16;
#pragma unroll
        for (int i = 0; i < 6; ++i) {
            int j = i * 256 + t;               // 1536 = 16 rows * 96
            int row = r0 + j / 96, col = j - (j / 96) * 96;
            int c8 = row / 448, rem = row - c8 * 448;
            int g = rem / 56, s = rem - g * 56;
            int ki = s >> 3, kj = s & 7;
            float v = 0.f;
            if (kj < 7) {
                int o = (c8 * 8 + g) * 49 + ki * 7 + kj;
                v = col < 64 ? w2[o * 64 + col] : (col == 64 ? b2[o] : 0.f);
            }
            w2b96[row * 96 + col] = f2hu(v);
        }
        return;
    }

    const int px0 = bid * 64;
    const int b = px0 / HW;
    const int p0 = px0 - b * HW;               // multiple of 64 (3136 % 64 == 0)

    {
        unsigned int* xw = (unsigned int*)xt;
#pragma unroll
        for (int s = 0; s < 4; ++s)
#pragma unroll
            for (int i = 0; i < 2; ++i) {
                int j = i * 256 + t;           // 512 jobs: (cpair, pixel-quad)
                int cp2 = j >> 2, pq = j & 3;
                const float* s0 = x + (size_t)(b * 256 + cp2 * 2) * HW
                                    + p0 + s * 16 + pq * 4;
                float4 v0 = *(const float4*)(s0);
                float4 v1 = *(const float4*)(s0 + HW);
                int pxb = s * 16 + pq * 4;
                xw[(pxb + 0) * 132 + cp2] = pkrtz(v0.x, v1.x);
                xw[(pxb + 1) * 132 + cp2] = pkrtz(v0.y, v1.y);
                xw[(pxb + 2) * 132 + cp2] = pkrtz(v0.z, v1.z);
                xw[(pxb + 3) * 132 + cp2] = pkrtz(v0.w, v1.w);
            }
    }
    if (t < 64) {
        unsigned short* yr = ytb + (size_t)(px0 + t) * YSTR + 64;
        ushort4 one; one.x = 0x3C00u; one.y = 0; one.z = 0; one.w = 0;
        ushort4 z; z.x = 0; z.y = 0; z.z = 0; z.w = 0;
        *(ushort4*)(yr) = one;
#pragma unroll
        for (int q = 1; q < 8; ++q) *(ushort4*)(yr + q * 4) = z;
    }
    __syncthreads();

    const int lane = t & 63, wave = t >> 6;
    const int n = lane & 15, quad = lane >> 4;
    const int m0 = wave * 16;

    h8 A[8];
#pragma unroll
    for (int k = 0; k < 8; ++k) {
        const float* wrow = w1 + (m0 + n) * 256 + k * 32 + quad * 8;
        float4 wa = *(const float4*)(wrow);
        float4 wb = *(const float4*)(wrow + 4);
        union { uint4 u; h8 h; } Au;
        Au.u.x = pkrtz(wa.x, wa.y);
        Au.u.y = pkrtz(wa.z, wa.w);
        Au.u.z = pkrtz(wb.x, wb.y);
        Au.u.w = pkrtz(wb.z, wb.w);
        A[k] = Au.h;
    }
    float sc[4], sh[4];
#pragma unroll
    for (int r = 0; r < 4; ++r) {
        int m = m0 + quad * 4 + r;
        sc[r] = gamma[m] * rsqrtf(var[m] + 1e-5f);
        sh[r] = beta[m] - mean[m] * sc[r] + b1[m] * sc[r];
    }

#pragma unroll
    for (int s = 0; s < 4; ++s) {
        f32x4 acc = {0.f, 0.f, 0.f, 0.f};
#pragma unroll
        for (int k = 0; k < 8; ++k) {
            h8 bv = *(const h8*)(&xt[(s * 16 + n) * 264 + k * 32 + quad * 8]);
            acc = __builtin_amdgcn_mfma_f32_16x16x32_f16(A[k], bv, acc, 0, 0, 0);
        }
        uint2 pk;
        pk.x = pkrtz(fmaxf(acc[0] * sc[0] + sh[0], 0.f),
                     fmaxf(acc[1] * sc[1] + sh[1], 0.f));
        pk.y = pkrtz(fmaxf(acc[2] * sc[2] + sh[2], 0.f),
                     fmaxf(acc[3] * sc[3] + sh[3], 0.f));
        *(uint2*)(ytb + (size_t)(px0 + s * 16 + n) * YSTR + m0 + quad * 4) = pk;
    }
}

// One (batch, 8-group chunk) per block; 4x8 pixel tile (32 px, two 16-px halves).
// Halved block count (3136) + phase-C loads reused across both halves
// -> per-pixel latency chain ~halves. LDS 38656 B -> 4 blocks/CU.
__global__ __launch_bounds__(256, 4) void kmain(
    const float* __restrict__ x, const unsigned short* __restrict__ w2b96,
    const unsigned short* __restrict__ ytb, float* __restrict__ out)
{
    __shared__ __align__(16) unsigned int smem_u[WGT32_W + 16 * XSEG];  // 38656 B
    unsigned short* wgt16 = (unsigned short*)smem_u;
    unsigned int* xsb = smem_u + WGT32_W;

    const int t = threadIdx.x;
    const int pix = t & 15, sub = t >> 4;
    const int lane = t & 63, wave = t >> 6;
    const int bc = blockIdx.x;
    const int b = bc >> 3, c8 = bc & 7;       // channels c8*32 .. +31 (8 groups)
    const int w0 = blockIdx.y * 8, h0 = blockIdx.z * 4;
    const int ph = pix >> 3, pw = pix & 7;    // 2 rows x 8 cols (within a half)
    const int n = lane & 15, quad = lane >> 4;

    // A: B-fragments from ytb for BOTH pixel halves (rows h0..h0+1, h0+2..h0+3)
    h8 bfa[3], bfb[3];
    {
        const int Pa = b * HW + (h0 + (n >> 3)) * 56 + w0 + (n & 7);
        const unsigned short* ya = ytb + (size_t)Pa * YSTR + quad * 8;
        bfa[0] = *(const h8*)(ya);
        bfa[1] = *(const h8*)(ya + 32);
        bfa[2] = *(const h8*)(ya + 64);
        const unsigned short* yb = ya + (size_t)112 * YSTR;  // +2 rows
        bfb[0] = *(const h8*)(yb);
        bfb[1] = *(const h8*)(yb + 32);
        bfb[2] = *(const h8*)(yb + 64);
    }

    // B: stage x halo: seg=(g,cp) x 10 rows (h0-3..h0+6); cols w0-3..w0+10.
    if (t < 160) {
        const int seg = t & 15, jr = t >> 4;   // jr 0..9
        const int jg = seg >> 1, jcp = seg & 1;
        const int hh = h0 + jr - 3;
        const bool rowok = (hh >= 0) && (hh < 56);
        const float* src = x + ((size_t)b * 256 + c8 * 32 + jg * 4 + jcp * 2) * HW + hh * 56;
        float4 va[2][4];
#pragma unroll
        for (int q = 0; q < 4; ++q) {
            int col0 = w0 - 4 + q * 4;
            bool ok = rowok && (col0 >= 0) && (col0 <= 52);
#pragma unroll
            for (int ci = 0; ci < 2; ++ci)
                va[ci][q] = ok ? *(const float4*)(src + ci * HW + col0)
                              : make_float4(0.f, 0.f, 0.f, 0.f);
        }
        unsigned int* dst = xsb + seg * XSEG + jr * XROW;
#pragma unroll
        for (int q = 0; q < 4; ++q)
#pragma unroll
            for (int e = 0; e < 4; ++e) {
                int c = q * 4 + e - 1;               // col index w0-3+c
                if (c >= 0 && c < 14)
                    dst[c] = pkrtz(fget(va[0][q], e), fget(va[1][q], e));
            }
    }

    // C: wgen: 448 slot-rows x 32 px. Each tile's A-fragments (3 global loads)
    //    serve BOTH pixel halves (6 MFMAs) -> load chain amortized 2x.
    {
        const int c0 = c8 * 448;
        for (int tile = wave; tile < 28; tile += 4) {
            const unsigned short* ap = w2b96 + (size_t)(c0 + tile * 16 + n) * 96 + quad * 8;
            h8 af0 = *(const h8*)(ap);
            h8 af1 = *(const h8*)(ap + 32);
            h8 af2 = *(const h8*)(ap + 64);
            f32x4 aca = {0.f, 0.f, 0.f, 0.f};
            aca = __builtin_amdgcn_mfma_f32_16x16x32_f16(af0, bfa[0], aca, 0, 0, 0);
            aca = __builtin_amdgcn_mfma_f32_16x16x32_f16(af1, bfa[1], aca, 0, 0, 0);
            aca = __builtin_amdgcn_mfma_f32_16x16x32_f16(af2, bfa[2], aca, 0, 0, 0);
            f32x4 acb = {0.f, 0.f, 0.f, 0.f};
            acb = __builtin_amdgcn_mfma_f32_16x16x32_f16(af0, bfb[0], acb, 0, 0, 0);
            acb = __builtin_amdgcn_mfma_f32_16x16x32_f16(af1, bfb[1], acb, 0, 0, 0);
            acb = __builtin_amdgcn_mfma_f32_16x16x32_f16(af2, bfb[2], acb, 0, 0, 0);
            uint2 pka, pkb;
            pka.x = pkrtz(aca[0], aca[1]);
            pka.y = pkrtz(aca[2], aca[3]);
            pkb.x = pkrtz(acb[0], acb[1]);
            pkb.y = pkrtz(acb[2], acb[3]);
            *(uint2*)(wgt16 + n * PS2 + tile * 16 + quad * 4) = pka;
            *(uint2*)(wgt16 + (16 + n) * PS2 + tile * 16 + quad * 4) = pkb;
        }
    }
    __syncthreads();    // the only barrier: xsb + wgt ready

    // D: involution: thread = (pixel pix, group g, cp); 2 pixels per thread
    //    (one per half). native v2f16 -> v_pk_fma_f16, op_sel broadcasts.
    const int g = sub & 7, cp = sub >> 3;
    const unsigned int* xrb = xsb + (g * 2 + cp) * XSEG + pw;
#pragma unroll
    for (int php = 0; php < 2; ++php) {
        const unsigned short* wr16 = wgt16 + (php * 16 + pix) * PS2 + g * 56;
        const unsigned int* xr = xrb + (php * 2 + ph) * XROW;
        h2v acA = {(_Float16)0.f, (_Float16)0.f};
        h2v acB = acA;
#pragma unroll
        for (int ki = 0; ki < 7; ++ki) {
            uint4 wq = *(const uint4*)(wr16 + ki * 8);
            const unsigned int* xrow = xr + ki * XROW;
            unsigned int xv[7];
#pragma unroll
            for (int j = 0; j < 7; ++j) xv[j] = xrow[j];
            h2v w01 = uh(wq.x), w23 = uh(wq.y), w45 = uh(wq.z), w6p = uh(wq.w);
            acA += BLO(w01) * uh(xv[0]);
            acB += BHI(w01) * uh(xv[1]);
            acA += BLO(w23) * uh(xv[2]);
            acB += BHI(w23) * uh(xv[3]);
            acA += BLO(w45) * uh(xv[4]);
            acB += BHI(w45) * uh(xv[5]);
            acA += BLO(w6p) * uh(xv[6]);
        }
        h2v acc2 = acA + acB;
        int h = h0 + php * 2 + ph;
        size_t ob = ((size_t)b * 256 + c8 * 32 + g * 4 + cp * 2) * HW + h * 56 + w0 + pw;
        out[ob] = (float)acc2[0];
        out[ob + HW] = (float)acc2[1];
    }
}

extern "C" void kernel_launch(void* const* d_in, const int* in_sizes, int n_in,
                              void* d_out, int out_size, void* d_ws, size_t ws_size,
                              hipStream_t stream) {
    const float* x     = (const float*)d_in[0];
    const float* w1    = (const float*)d_in[1];
    const float* b1    = (const float*)d_in[2];
    const float* gamma = (const float*)d_in[3];
    const float* beta  = (const float*)d_in[4];
    const float* mean  = (const float*)d_in[5];
    const float* var   = (const float*)d_in[6];
    const float* w2    = (const float*)d_in[7];
    const float* b2    = (const float*)d_in[8];
    float* out = (float*)d_out;

    unsigned short* ytb   = (unsigned short*)d_ws;         // 12544*96 u16
    unsigned short* w2b96 = ytb + (size_t)NPX * YSTR;      // 3584*96 u16 (permuted rows)
    hipLaunchKernelGGL(kyw, dim3(420), dim3(256), 0, stream,
                       x, w1, b1, gamma, beta, mean, var, w2, b2, ytb, w2b96);
    hipLaunchKernelGGL(kmain, dim3(32, 7, 14), dim3(256), 0, stream,
                       x, w2b96, ytb, out);
}

// Round 10
// 118.638 us; speedup vs baseline: 1.3496x; 1.0257x over previous
//
#include <hip/hip_runtime.h>
#include <hip/hip_fp16.h>

typedef _Float16 h8 __attribute__((ext_vector_type(8)));
typedef _Float16 h2v __attribute__((ext_vector_type(2)));
typedef __fp16 fp16x2 __attribute__((ext_vector_type(2)));
typedef float f32x4 __attribute__((ext_vector_type(4)));

#define HW 3136    // 56*56
#define NPX 12544  // B*HW
#define YSTR 96    // ytb row stride: 64 y + [1, 0..0] b2 lane
#define XROW 14    // xsb row stride (u32)
#define XSEG 148   // xsb segment stride (u32): >=10*14; 2*148%32==8 -> phase-D x reads
                   //   are a per-half-wave bank permutation (free)
#define PS2 456    // wgt pixel stride (u16): 448 slots + 8 pad; 912B, 16B-aligned
#define WGT_W 3648 // wgt region words: 16 px * 228 (one pixel-half at a time)
// LDS: 3648*4 + 16*148*4 = 14592 + 9472 = 24064 B -> 6 blocks/CU (24 waves)
// 32-px tile amortization kept by holding half-B weights in registers (7x uint2).

union UH { unsigned int u; h2v h; fp16x2 p; };
__device__ __forceinline__ h2v uh(unsigned int u) { UH v; v.u = u; return v.h; }
__device__ __forceinline__ unsigned int hu(h2v h) { UH v; v.h = h; return v.u; }
#define BLO(w) __builtin_shufflevector(w, w, 0, 0)
#define BHI(w) __builtin_shufflevector(w, w, 1, 1)

__device__ __forceinline__ unsigned int pkrtz(float a, float b) {
    UH v; v.p = __builtin_amdgcn_cvt_pkrtz(a, b); return v.u;
}
__device__ __forceinline__ unsigned short f2hu(float f) {
    union { __half h; unsigned short u; } v; v.h = __float2half(f); return v.u;
}
__device__ __forceinline__ float fget(const float4& v, int e) {
    return e == 0 ? v.x : e == 1 ? v.y : e == 2 ? v.z : v.w;
}

// Merged prep + y-GEMM (all f16).  [unchanged from R7: ~8-9 us]
// blocks 0..195: y = relu(bn(w1 @ x)) for 64 px each -> ytb[px][96]
// blocks 196..419: w2b96[row'][96] = f16([w2 | b2 | 0..]) slot-permuted:
//   row' = c8*448 + g*56 + ki*8 + kj (kj==7 rows zeroed) <-> w2 row (c8*8+g)*49 + ki*7 + kj
__global__ __launch_bounds__(256) void kyw(
    const float* __restrict__ x, const float* __restrict__ w1,
    const float* __restrict__ b1, const float* __restrict__ gamma,
    const float* __restrict__ beta, const float* __restrict__ mean,
    const float* __restrict__ var, const float* __restrict__ w2,
    const float* __restrict__ b2, unsigned short* __restrict__ ytb,
    unsigned short* __restrict__ w2b96)
{
    __shared__ unsigned short xt[64 * 264];    // [px][ch], stride 264 (u32 view: 132)
    const int t = threadIdx.x, bid = blockIdx.x;

    if (bid >= 196) {                          // w2 -> f16 K=96 rows, permuted
        const int r0 = (bid - 196) * 16;
#pragma unroll
        for (int i = 0; i < 6; ++i) {
            int j = i * 256 + t;               // 1536 = 16 rows * 96
            int row = r0 + j / 96, col = j - (j / 96) * 96;
            int c8 = row / 448, rem = row - c8 * 448;
            int g = rem / 56, s = rem - g * 56;
            int ki = s >> 3, kj = s & 7;
            float v = 0.f;
            if (kj < 7) {
                int o = (c8 * 8 + g) * 49 + ki * 7 + kj;
                v = col < 64 ? w2[o * 64 + col] : (col == 64 ? b2[o] : 0.f);
            }
            w2b96[row * 96 + col] = f2hu(v);
        }
        return;
    }

    const int px0 = bid * 64;
    const int b = px0 / HW;
    const int p0 = px0 - b * HW;               // multiple of 64 (3136 % 64 == 0)

    {
        unsigned int* xw = (unsigned int*)xt;
#pragma unroll
        for (int s = 0; s < 4; ++s)
#pragma unroll
            for (int i = 0; i < 2; ++i) {
                int j = i * 256 + t;           // 512 jobs: (cpair, pixel-quad)
                int cp2 = j >> 2, pq = j & 3;
                const float* s0 = x + (size_t)(b * 256 + cp2 * 2) * HW
                                    + p0 + s * 16 + pq * 4;
                float4 v0 = *(const float4*)(s0);
                float4 v1 = *(const float4*)(s0 + HW);
                int pxb = s * 16 + pq * 4;
                xw[(pxb + 0) * 132 + cp2] = pkrtz(v0.x, v1.x);
                xw[(pxb + 1) * 132 + cp2] = pkrtz(v0.y, v1.y);
                xw[(pxb + 2) * 132 + cp2] = pkrtz(v0.z, v1.z);
                xw[(pxb + 3) * 132 + cp2] = pkrtz(v0.w, v1.w);
            }
    }
    if (t < 64) {
        unsigned short* yr = ytb + (size_t)(px0 + t) * YSTR + 64;
        ushort4 one; one.x = 0x3C00u; one.y = 0; one.z = 0; one.w = 0;
        ushort4 z; z.x = 0; z.y = 0; z.z = 0; z.w = 0;
        *(ushort4*)(yr) = one;
#pragma unroll
        for (int q = 1; q < 8; ++q) *(ushort4*)(yr + q * 4) = z;
    }
    __syncthreads();

    const int lane = t & 63, wave = t >> 6;
    const int n = lane & 15, quad = lane >> 4;
    const int m0 = wave * 16;

    h8 A[8];
#pragma unroll
    for (int k = 0; k < 8; ++k) {
        const float* wrow = w1 + (m0 + n) * 256 + k * 32 + quad * 8;
        float4 wa = *(const float4*)(wrow);
        float4 wb = *(const float4*)(wrow + 4);
        union { uint4 u; h8 h; } Au;
        Au.u.x = pkrtz(wa.x, wa.y);
        Au.u.y = pkrtz(wa.z, wa.w);
        Au.u.z = pkrtz(wb.x, wb.y);
        Au.u.w = pkrtz(wb.z, wb.w);
        A[k] = Au.h;
    }
    float sc[4], sh[4];
#pragma unroll
    for (int r = 0; r < 4; ++r) {
        int m = m0 + quad * 4 + r;
        sc[r] = gamma[m] * rsqrtf(var[m] + 1e-5f);
        sh[r] = beta[m] - mean[m] * sc[r] + b1[m] * sc[r];
    }

#pragma unroll
    for (int s = 0; s < 4; ++s) {
        f32x4 acc = {0.f, 0.f, 0.f, 0.f};
#pragma unroll
        for (int k = 0; k < 8; ++k) {
            h8 bv = *(const h8*)(&xt[(s * 16 + n) * 264 + k * 32 + quad * 8]);
            acc = __builtin_amdgcn_mfma_f32_16x16x32_f16(A[k], bv, acc, 0, 0, 0);
        }
        uint2 pk;
        pk.x = pkrtz(fmaxf(acc[0] * sc[0] + sh[0], 0.f),
                     fmaxf(acc[1] * sc[1] + sh[1], 0.f));
        pk.y = pkrtz(fmaxf(acc[2] * sc[2] + sh[2], 0.f),
                     fmaxf(acc[3] * sc[3] + sh[3], 0.f));
        *(uint2*)(ytb + (size_t)(px0 + s * 16 + n) * YSTR + m0 + quad * 4) = pk;
    }
}

// One (batch, 8-group chunk) per block; 4x8 pixel tile (32 px) but only HALF the
// weights live in LDS at a time (half-B packed in 14 VGPRs) -> LDS 24064 B,
// 6 blocks/CU (24 waves) WITH the 2x load-chain amortization. grid (32, 7, 14).
__global__ __launch_bounds__(256, 6) void kmain(
    const float* __restrict__ x, const unsigned short* __restrict__ w2b96,
    const unsigned short* __restrict__ ytb, float* __restrict__ out)
{
    __shared__ __align__(16) unsigned int smem_u[WGT_W + 16 * XSEG];  // 24064 B
    unsigned short* wgt16 = (unsigned short*)smem_u;
    unsigned int* xsb = smem_u + WGT_W;

    const int t = threadIdx.x;
    const int pix = t & 15, sub = t >> 4;
    const int lane = t & 63, wave = t >> 6;
    const int bc = blockIdx.x;
    const int b = bc >> 3, c8 = bc & 7;       // channels c8*32 .. +31 (8 groups)
    const int w0 = blockIdx.y * 8, h0 = blockIdx.z * 4;
    const int ph = pix >> 3, pw = pix & 7;    // 2 rows x 8 cols (within a half)
    const int n = lane & 15, quad = lane >> 4;

    // A: B-fragments from ytb for BOTH pixel halves (rows h0..h0+1, h0+2..h0+3)
    h8 bfa[3], bfb[3];
    {
        const int Pa = b * HW + (h0 + (n >> 3)) * 56 + w0 + (n & 7);
        const unsigned short* ya = ytb + (size_t)Pa * YSTR + quad * 8;
        bfa[0] = *(const h8*)(ya);
        bfa[1] = *(const h8*)(ya + 32);
        bfa[2] = *(const h8*)(ya + 64);
        const unsigned short* yb2 = ya + (size_t)112 * YSTR;  // +2 rows
        bfb[0] = *(const h8*)(yb2);
        bfb[1] = *(const h8*)(yb2 + 32);
        bfb[2] = *(const h8*)(yb2 + 64);
    }

    // B: stage x halo: seg=(g,cp) x 10 rows (h0-3..h0+6); cols w0-3..w0+10.
    if (t < 160) {
        const int seg = t & 15, jr = t >> 4;   // jr 0..9
        const int jg = seg >> 1, jcp = seg & 1;
        const int hh = h0 + jr - 3;
        const bool rowok = (hh >= 0) && (hh < 56);
        const float* src = x + ((size_t)b * 256 + c8 * 32 + jg * 4 + jcp * 2) * HW + hh * 56;
        float4 va[2][4];
#pragma unroll
        for (int q = 0; q < 4; ++q) {
            int col0 = w0 - 4 + q * 4;
            bool ok = rowok && (col0 >= 0) && (col0 <= 52);
#pragma unroll
            for (int ci = 0; ci < 2; ++ci)
                va[ci][q] = ok ? *(const float4*)(src + ci * HW + col0)
                              : make_float4(0.f, 0.f, 0.f, 0.f);
        }
        unsigned int* dst = xsb + seg * XSEG + jr * XROW;
#pragma unroll
        for (int q = 0; q < 4; ++q)
#pragma unroll
            for (int e = 0; e < 4; ++e) {
                int c = q * 4 + e - 1;               // col index w0-3+c
                if (c >= 0 && c < 14)
                    dst[c] = pkrtz(fget(va[0][q], e), fget(va[1][q], e));
            }
    }

    // C: wgen: each tile's 3 A-fragment loads serve BOTH halves (6 MFMAs).
    //    Half-A -> LDS now; half-B packed into pkb[7] (14 VGPRs), written later.
    uint2 pkb[7];
    {
        const int c0 = c8 * 448;
#pragma unroll
        for (int j = 0; j < 7; ++j) {
            const int tile = wave + 4 * j;
            const unsigned short* ap = w2b96 + (size_t)(c0 + tile * 16 + n) * 96 + quad * 8;
            h8 af0 = *(const h8*)(ap);
            h8 af1 = *(const h8*)(ap + 32);
            h8 af2 = *(const h8*)(ap + 64);
            f32x4 aca = {0.f, 0.f, 0.f, 0.f};
            aca = __builtin_amdgcn_mfma_f32_16x16x32_f16(af0, bfa[0], aca, 0, 0, 0);
            aca = __builtin_amdgcn_mfma_f32_16x16x32_f16(af1, bfa[1], aca, 0, 0, 0);
            aca = __builtin_amdgcn_mfma_f32_16x16x32_f16(af2, bfa[2], aca, 0, 0, 0);
            f32x4 acb = {0.f, 0.f, 0.f, 0.f};
            acb = __builtin_amdgcn_mfma_f32_16x16x32_f16(af0, bfb[0], acb, 0, 0, 0);
            acb = __builtin_amdgcn_mfma_f32_16x16x32_f16(af1, bfb[1], acb, 0, 0, 0);
            acb = __builtin_amdgcn_mfma_f32_16x16x32_f16(af2, bfb[2], acb, 0, 0, 0);
            uint2 pka;
            pka.x = pkrtz(aca[0], aca[1]);
            pka.y = pkrtz(aca[2], aca[3]);
            pkb[j].x = pkrtz(acb[0], acb[1]);
            pkb[j].y = pkrtz(acb[2], acb[3]);
            *(uint2*)(wgt16 + n * PS2 + tile * 16 + quad * 4) = pka;
        }
    }
    __syncthreads();    // xsb + wgt(half A) ready

    const int g = sub & 7, cp = sub >> 3;
    const unsigned int* xrb = xsb + (g * 2 + cp) * XSEG + pw;
    const unsigned short* wr16 = wgt16 + pix * PS2 + g * 56;

    // D-A: involution for pixel half A (output rows h0+0..h0+1)
    {
        const unsigned int* xr = xrb + ph * XROW;
        h2v acA = {(_Float16)0.f, (_Float16)0.f};
        h2v acB = acA;
#pragma unroll
        for (int ki = 0; ki < 7; ++ki) {
            uint4 wq = *(const uint4*)(wr16 + ki * 8);
            const unsigned int* xrow = xr + ki * XROW;
            unsigned int xv[7];
#pragma unroll
            for (int j = 0; j < 7; ++j) xv[j] = xrow[j];
            h2v w01 = uh(wq.x), w23 = uh(wq.y), w45 = uh(wq.z), w6p = uh(wq.w);
            acA += BLO(w01) * uh(xv[0]);
            acB += BHI(w01) * uh(xv[1]);
            acA += BLO(w23) * uh(xv[2]);
            acB += BHI(w23) * uh(xv[3]);
            acA += BLO(w45) * uh(xv[4]);
            acB += BHI(w45) * uh(xv[5]);
            acA += BLO(w6p) * uh(xv[6]);
        }
        h2v acc2 = acA + acB;
        size_t ob = ((size_t)b * 256 + c8 * 32 + g * 4 + cp * 2) * HW
                  + (h0 + ph) * 56 + w0 + pw;
        out[ob] = (float)acc2[0];
        out[ob + HW] = (float)acc2[1];
    }
    __syncthreads();    // all reads of wgt(half A) done

    // C2: dump half-B weights from registers into the same wgt region
    {
#pragma unroll
        for (int j = 0; j < 7; ++j) {
            const int tile = wave + 4 * j;
            *(uint2*)(wgt16 + n * PS2 + tile * 16 + quad * 4) = pkb[j];
        }
    }
    __syncthreads();    // wgt(half B) ready

    // D-B: involution for pixel half B (output rows h0+2..h0+3)
    {
        const unsigned int* xr = xrb + (2 + ph) * XROW;
        h2v acA = {(_Float16)0.f, (_Float16)0.f};
        h2v acB = acA;
#pragma unroll
        for (int ki = 0; ki < 7; ++ki) {
            uint4 wq = *(const uint4*)(wr16 + ki * 8);
            const unsigned int* xrow = xr + ki * XROW;
            unsigned int xv[7];
#pragma unroll
            for (int j = 0; j < 7; ++j) xv[j] = xrow[j];
            h2v w01 = uh(wq.x), w23 = uh(wq.y), w45 = uh(wq.z), w6p = uh(wq.w);
            acA += BLO(w01) * uh(xv[0]);
            acB += BHI(w01) * uh(xv[1]);
            acA += BLO(w23) * uh(xv[2]);
            acB += BHI(w23) * uh(xv[3]);
            acA += BLO(w45) * uh(xv[4]);
            acB += BHI(w45) * uh(xv[5]);
            acA += BLO(w6p) * uh(xv[6]);
        }
        h2v acc2 = acA + acB;
        size_t ob = ((size_t)b * 256 + c8 * 32 + g * 4 + cp * 2) * HW
                  + (h0 + 2 + ph) * 56 + w0 + pw;
        out[ob] = (float)acc2[0];
        out[ob + HW] = (float)acc2[1];
    }
}

extern "C" void kernel_launch(void* const* d_in, const int* in_sizes, int n_in,
                              void* d_out, int out_size, void* d_ws, size_t ws_size,
                              hipStream_t stream) {
    const float* x     = (const float*)d_in[0];
    const float* w1    = (const float*)d_in[1];
    const float* b1    = (const float*)d_in[2];
    const float* gamma = (const float*)d_in[3];
    const float* beta  = (const float*)d_in[4];
    const float* mean  = (const float*)d_in[5];
    const float* var   = (const float*)d_in[6];
    const float* w2    = (const float*)d_in[7];
    const float* b2    = (const float*)d_in[8];
    float* out = (float*)d_out;

    unsigned short* ytb   = (unsigned short*)d_ws;         // 12544*96 u16
    unsigned short* w2b96 = ytb + (size_t)NPX * YSTR;      // 3584*96 u16 (permuted rows)
    hipLaunchKernelGGL(kyw, dim3(420), dim3(256), 0, stream,
                       x, w1, b1, gamma, beta, mean, var, w2, b2, ytb, w2b96);
    hipLaunchKernelGGL(kmain, dim3(32, 7, 14), dim3(256), 0, stream,
                       x, w2b96, ytb, out);
}